// Round 11
// baseline (469.077 us; speedup 1.0000x reference)
//
#include <hip/hip_runtime.h>
#include <math.h>

typedef __bf16 bf16x8 __attribute__((ext_vector_type(8)));
typedef float f32x4 __attribute__((ext_vector_type(4)));
typedef unsigned short ushort_t;

static __device__ __forceinline__ unsigned short f2bf(float f) {
  union { float f; unsigned int u; } c; c.f = f;
  unsigned int u = c.u;
  unsigned int r = u + 0x7FFFu + ((u >> 16) & 1u);
  return (unsigned short)(r >> 16);
}

// ---------------- constants ----------------
#define CDIM 180      // true channel dim
#define CPAD 192      // padded: 6 heads * 32
#define NTOK 65536

// scale * log2(e), folded into Q weights/bias at prep: p = exp2(S)
#define SCL2E 0.26339361f

// pack two f32's high halves into packed bf16 pair (truncating): D = {hi16(b), hi16(a)}
static __device__ __forceinline__ unsigned pk_bf(float a, float b) {
  union { float f; unsigned u; } ca, cb; ca.f = a; cb.f = b;
  return __builtin_amdgcn_perm(cb.u, ca.u, 0x07060302u);
}

// ---------------- prep ----------------
// Wt stored in WAVE-COALESCED W2 layout (round-9/10: n-major [n][k] made
// every gemm B-load a 16-segment gather; request count was the bottleneck).
// W2 chunk = (((tile*2+wn)*2+nt)*6+ks)*512 + lane*8 ushorts: one wave's
// B-fragment load = 1024 contiguous bytes.
//   wqkvt: 9 tiles (n<192: Q *SCL2E; 192..383: K; 384..575: V), 110592 elems
//   pwt:   3 tiles, 36864 elems
// qkvb[576] (Q part *SCL2E), pbp[192], k_bias_row[192] (-> k_tok row NTOK),
// vt4 bias group (tok NTOK).
__global__ __launch_bounds__(256) void prep_k(
    const float* __restrict__ q_w, const float* __restrict__ q_b,
    const float* __restrict__ kv_w, const float* __restrict__ kv_b,
    const float* __restrict__ p_w, const float* __restrict__ p_b,
    ushort_t* __restrict__ wqkvt, ushort_t* __restrict__ pwt,
    float* __restrict__ qkvb, float* __restrict__ pbp,
    ushort_t* __restrict__ k_bias_row, ushort_t* __restrict__ vt4_bias_grp)
{
  int i = blockIdx.x * 256 + threadIdx.x;
  if (i < 110592) { // wqkvt, W2 layout
    int r = i & 7, i8 = i >> 3;
    int lane = i8 & 63, t1 = i8 >> 6;
    int ks = t1 % 6, t2 = t1 / 6;
    int nt = t2 & 1, wn = (t2 >> 1) & 1, tile = t2 >> 2;
    int n = tile * 64 + wn * 32 + nt * 16 + (lane & 15);
    int k = ks * 32 + (lane >> 4) * 8 + r;
    float v = 0.f;
    if (k < CDIM) {
      if (n < 192) { int h = n >> 5, d = n & 31; if (d < 30) v = q_w[k * CDIM + h * 30 + d] * SCL2E; }
      else { int cn = n - 192; int part = cn >= 192; int c2 = cn - part * 192;
             int h = c2 >> 5, d = c2 & 31;
             if (d < 30) v = kv_w[k * 360 + part * 180 + h * 30 + d]; }
    }
    wqkvt[i] = f2bf(v);
    return;
  }
  i -= 110592;
  if (i < 36864) { // pwt, W2 layout (3 tiles)
    int r = i & 7, i8 = i >> 3;
    int lane = i8 & 63, t1 = i8 >> 6;
    int ks = t1 % 6, t2 = t1 / 6;
    int nt = t2 & 1, wn = (t2 >> 1) & 1, tile = t2 >> 2;
    int n = tile * 64 + wn * 32 + nt * 16 + (lane & 15);
    int k = ks * 32 + (lane >> 4) * 8 + r;
    int h = k >> 5, d = k & 31;
    float v = (d < 30 && n < CDIM) ? p_w[(h * 30 + d) * CDIM + n] : 0.f;
    pwt[i] = f2bf(v);
    return;
  }
  i -= 36864;
  if (i < 576) {
    float v = 0.f;
    if (i < 192) { int h = i >> 5, d = i & 31; if (d < 30) v = q_b[h * 30 + d] * SCL2E; }
    else { int cn = i - 192; int part = cn >= 192; int c2 = cn - part * 192;
           int h = c2 >> 5, d = c2 & 31;
           if (d < 30) v = kv_b[part * 180 + h * 30 + d];
           else if (part == 1 && d == 30) v = 1.0f; }  // ones-column -> row-sum l
    qkvb[i] = v;
    return;
  }
  i -= 576;
  if (i < 192) { pbp[i] = (i < CDIM) ? p_b[i] : 0.f; return; }
  i -= 192;
  if (i < 192) { // K bias row (zero-padded positions: xn==0 -> k = bias)
    int h = i >> 5, d = i & 31;
    k_bias_row[i] = (d < 30) ? f2bf(kv_b[h * 30 + d]) : (ushort_t)0;
    return;
  }
  i -= 192;
  if (i < 768) { // vt4 bias group at tok==NTOK: [192 d][4]
    int d = i >> 2, h = d >> 5, dd = d & 31;
    float v = 0.f;
    if (dd < 30) v = kv_b[180 + h * 30 + dd];
    else if (dd == 30) v = 1.0f;
    vt4_bias_grp[i] = f2bf(v);
    return;
  }
}

// ---------------- fused GEMM: BM=128, coalesced W2 B-loads ----------
// B-load per wave = 1024B contiguous (W2 layout) -> single-segment stream.
// Depth-2 register pipeline on B.
// MODE 0: A-tile built by FUSED LAYERNORM from x f32 (16-lane-group LN,
//         f2bf rounding matches old ln_k exactly). 9 n-tiles:
//         n<192 -> q_tok; 192..383 -> k_tok; 384..575 -> vt4.
// MODE 1: A=ao (bf16), Wt=pwt, 3 n-tiles: d_out f32 + residual x
template<int MODE>
__global__ __launch_bounds__(256) void gemm_k(const ushort_t* __restrict__ A,
    const float* __restrict__ x, const float* __restrict__ nw, const float* __restrict__ nb,
    const ushort_t* __restrict__ Wt, const float* __restrict__ bias,
    ushort_t* __restrict__ q_out, ushort_t* __restrict__ k_out,
    ushort_t* __restrict__ vt_out,
    float* __restrict__ outf, const float* __restrict__ resid)
{
  constexpr int NT = (MODE == 0) ? 9 : 3;
  __shared__ __align__(16) ushort_t aS[128 * 200];
  const int tid = threadIdx.x;
  const int lane = tid & 63, wave = tid >> 6;
  const int quad = lane >> 4, l16 = lane & 15;
  const int wm = wave & 1, wn = wave >> 1;
  const int bm = blockIdx.x;

  if constexpr (MODE == 0) {
    // ---- fused LayerNorm staging: 128 rows of x[.][180] f32 -> bf16 aS ----
    const float* xb = x + (size_t)bm * 128 * CDIM;
    const int grp = tid >> 4, gl = tid & 15;
    float wv[12], bvv[12];
    if (gl < 15) {
      #pragma unroll
      for (int e = 0; e < 3; ++e) {
        float4 w4 = *reinterpret_cast<const float4*>(nw + gl * 12 + e * 4);
        float4 b4 = *reinterpret_cast<const float4*>(nb + gl * 12 + e * 4);
        wv[e*4+0] = w4.x; wv[e*4+1] = w4.y; wv[e*4+2] = w4.z; wv[e*4+3] = w4.w;
        bvv[e*4+0] = b4.x; bvv[e*4+1] = b4.y; bvv[e*4+2] = b4.z; bvv[e*4+3] = b4.w;
      }
    } else {
      #pragma unroll
      for (int k = 0; k < 12; ++k) { wv[k] = 0.f; bvv[k] = 0.f; }
    }
    #pragma unroll 2
    for (int i = 0; i < 8; ++i) {
      const int row = i * 16 + grp;
      const float* xr = xb + (size_t)row * CDIM;
      float v[12];
      float sum = 0.f, sq = 0.f;
      if (gl < 15) {
        #pragma unroll
        for (int e = 0; e < 3; ++e) {
          float4 x4 = *reinterpret_cast<const float4*>(xr + gl * 12 + e * 4);
          v[e*4+0] = x4.x; v[e*4+1] = x4.y; v[e*4+2] = x4.z; v[e*4+3] = x4.w;
        }
        #pragma unroll
        for (int k = 0; k < 12; ++k) { sum += v[k]; sq += v[k] * v[k]; }
      } else {
        #pragma unroll
        for (int k = 0; k < 12; ++k) v[k] = 0.f;
      }
      #pragma unroll
      for (int off = 1; off < 16; off <<= 1) {
        sum += __shfl_xor(sum, off, 64);
        sq  += __shfl_xor(sq, off, 64);
      }
      const float inv_n = 1.0f / 180.0f;
      float mean = sum * inv_n;
      float var = sq * inv_n - mean * mean;
      float rs = rsqrtf(var + 1e-5f);
      unsigned u[6];
      #pragma unroll
      for (int p = 0; p < 6; ++p) {
        float a = (v[2*p]   - mean) * rs * wv[2*p]   + bvv[2*p];
        float b = (v[2*p+1] - mean) * rs * wv[2*p+1] + bvv[2*p+1];
        u[p] = (unsigned)f2bf(a) | ((unsigned)f2bf(b) << 16);
      }
      ushort_t* dst = &aS[row * 200 + gl * 12];
      uint2 w01; w01.x = u[0]; w01.y = u[1];
      uint2 w23; w23.x = u[2]; w23.y = u[3];
      uint2 w45; w45.x = u[4]; w45.y = u[5];
      *reinterpret_cast<uint2*>(dst)     = w01;
      *reinterpret_cast<uint2*>(dst + 4) = w23;
      *reinterpret_cast<uint2*>(dst + 8) = w45;
    }
  } else {
    // stage full A tile: 128 rows x 192 cols (bf16 input)
    const ushort_t* Ab = A + (size_t)bm * 128 * 192;
    #pragma unroll
    for (int it = 0; it < 12; ++it) {
      int f = it * 256 + tid;
      int row = f / 24, kq = f % 24;
      uint4 v = *reinterpret_cast<const uint4*>(Ab + row * 192 + kq * 8);
      *reinterpret_cast<uint4*>(&aS[row * 200 + kq * 8]) = v;
    }
  }
  __syncthreads();  // the only barrier

  // W2 B-load: chunk (((tile*2+wn)*2+nt)*6+ks)*512 + lane*8; nt stride 3072
  auto ldB = [&](int tile, int ks, bf16x8* dst) {
    const ushort_t* p = Wt + (size_t)((tile * 2 + wn) * 12 + ks) * 512 + lane * 8;
    dst[0] = *reinterpret_cast<const bf16x8*>(p);
    dst[1] = *reinterpret_cast<const bf16x8*>(p + 3072);
  };

  bf16x8 bB0[2], bB1[2], bB2[2];
  ldB(0, 0, bB0);
  ldB(0, 1, bB1);

  for (int nt0 = 0; nt0 < NT; ++nt0) {
    const int ntn = (nt0 + 1 < NT) ? nt0 + 1 : 0;   // wrap: harmless redundant loads
    f32x4 acc[4][2] = {};

    // step KS: prefetch (PT,PKS) into PRE, compute with CUR
    #define GSTEP(KS, CUR, PRE, PT, PKS) do { \
      ldB(PT, PKS, PRE); \
      bf16x8 af[4]; \
      _Pragma("unroll") \
      for (int mt = 0; mt < 4; ++mt) \
        af[mt] = *reinterpret_cast<const bf16x8*>(&aS[(wm * 64 + mt * 16 + l16) * 200 + KS * 32 + quad * 8]); \
      _Pragma("unroll") \
      for (int mt = 0; mt < 4; ++mt) { \
        acc[mt][0] = __builtin_amdgcn_mfma_f32_16x16x32_bf16(af[mt], CUR[0], acc[mt][0], 0, 0, 0); \
        acc[mt][1] = __builtin_amdgcn_mfma_f32_16x16x32_bf16(af[mt], CUR[1], acc[mt][1], 0, 0, 0); \
      } \
    } while (0)

    GSTEP(0, bB0, bB2, nt0, 2);
    GSTEP(1, bB1, bB0, nt0, 3);
    GSTEP(2, bB2, bB1, nt0, 4);
    GSTEP(3, bB0, bB2, nt0, 5);
    GSTEP(4, bB1, bB0, ntn, 0);
    GSTEP(5, bB2, bB1, ntn, 1);
    #undef GSTEP

    // epilogue for this n-tile (also covers the cross-tile prefetches)
    #pragma unroll
    for (int mt = 0; mt < 4; ++mt) {
      int row = bm * 128 + wm * 64 + mt * 16 + quad * 4;
      #pragma unroll
      for (int nt = 0; nt < 2; ++nt) {
        int ncol = nt0 * 64 + wn * 32 + nt * 16 + l16;
        float bv = bias[ncol];
        if (MODE == 0 && nt0 >= 6) {
          // V part: 4 consecutive tokens (row..row+3, row%4==0) for dim d
          int d = ncol - 384;
          unsigned p0 = pk_bf(acc[mt][nt][0] + bv, acc[mt][nt][1] + bv);
          unsigned p1 = pk_bf(acc[mt][nt][2] + bv, acc[mt][nt][3] + bv);
          uint2 val; val.x = p0; val.y = p1;
          // vt4 index = tok*192 rearranged: (tok>>2)*768 + d*4 + (tok&3)
          *reinterpret_cast<uint2*>(vt_out + (size_t)row * 192 + d * 4) = val;
        } else {
          #pragma unroll
          for (int r = 0; r < 4; ++r) {
            int rr = row + r;
            float v = acc[mt][nt][r] + bv;
            if (MODE == 0) {
              if (ncol < 192) q_out[(size_t)rr * CPAD + ncol] = f2bf(v);
              else k_out[(size_t)rr * CPAD + (ncol - 192)] = f2bf(v);
            } else {
              if (ncol < CDIM) outf[(size_t)rr * CDIM + ncol] = v + resid[(size_t)rr * CDIM + ncol];
            }
          }
        }
      }
    }
  }
}

// ---------------- attention: 1-WAVE BLOCKS (round-11) ----------------------
// Kernel uses zero LDS and zero barriers; the 4 waves of the old 256-thread
// block shared nothing. 1-wave blocks (grid 256x6x4, 64 threads) give the
// scheduler 6144 independently placeable units -> refillable backlog, target
// 6 waves/SIMD (launch_bounds(64,6), VGPR cap ~85 >= current 64). Fixes the
// 32% occupancy that left the per-c dependency chain (load->QK->exp2->pack
// ->PV) exposed.
// S^T = K·Q^T; C-layout of S^T == A-layout of PV MFMA under key permutation
// key(kt,m) = 8*(m>>2) + 4*kt + (m&3). V in group-of-4 layout vt4; OOB ->
// bias group/row at tok NTOK. Fixed-max softmax (Q pre-scaled); l via V
// ones-column (d30). Interior: clamp-free offsets, depth-2 pipeline.
// Border: clamped depth-1 ping-pong.
__global__ __launch_bounds__(64, 6) void attn_k(const ushort_t* __restrict__ q_tok,
    const ushort_t* __restrict__ k_tok, const ushort_t* __restrict__ vt4,
    ushort_t* __restrict__ ao)
{
  const int w = blockIdx.x, h = blockIdx.y;
  const int wave = blockIdx.z;
  const int lane = threadIdx.x & 63;
  const int quad = lane >> 4, l16 = lane & 15;
  const int wy = w >> 4, wx = w & 15;
  const int tok0 = wy * 16 * 256 + wx * 16;
  const int hc = h * 32;
  const int ybase = wy * 16 - 4, xbase = wx * 16 - 4;

  // Q fragments (B-operand layout), 4 q-tiles of 16
  bf16x8 qf[4];
  #pragma unroll
  for (int qt = 0; qt < 4; ++qt) {
    int qi = wave * 64 + qt * 16 + l16;
    int token = tok0 + (qi >> 4) * 256 + (qi & 15);
    qf[qt] = *reinterpret_cast<const bf16x8*>(q_tok + (size_t)token * CPAD + hc + quad * 8);
  }

  // permuted key id for the K A-frag gather
  const int key0 = ((l16 >> 2) << 3) + (l16 & 3);

  f32x4 o[4][2] = {};
  f32x4 zero = {0.f, 0.f, 0.f, 0.f};

  // shared compute step: S^T = K Q^T (pre-scaled), raw v_exp, pack P, PV
  auto compute = [&](const bf16x8* kf, const uint2* va, const uint2* vb) {
    bf16x8 vf0, vf1;
    {
      union { unsigned u[4]; bf16x8 v; } a_;
      a_.u[0] = va[0].x; a_.u[1] = va[0].y; a_.u[2] = va[1].x; a_.u[3] = va[1].y;
      vf0 = a_.v;
      a_.u[0] = vb[0].x; a_.u[1] = vb[0].y; a_.u[2] = vb[1].x; a_.u[3] = vb[1].y;
      vf1 = a_.v;
    }
    __builtin_amdgcn_s_setprio(1);
    #pragma unroll
    for (int qt = 0; qt < 4; ++qt) {
      f32x4 s0 = __builtin_amdgcn_mfma_f32_16x16x32_bf16(kf[0], qf[qt], zero, 0, 0, 0);
      f32x4 s1 = __builtin_amdgcn_mfma_f32_16x16x32_bf16(kf[1], qf[qt], zero, 0, 0, 0);
      union { unsigned u[4]; bf16x8 v; } pk;
      pk.u[0] = pk_bf(__builtin_amdgcn_exp2f(s0[0]), __builtin_amdgcn_exp2f(s0[1]));
      pk.u[1] = pk_bf(__builtin_amdgcn_exp2f(s0[2]), __builtin_amdgcn_exp2f(s0[3]));
      pk.u[2] = pk_bf(__builtin_amdgcn_exp2f(s1[0]), __builtin_amdgcn_exp2f(s1[1]));
      pk.u[3] = pk_bf(__builtin_amdgcn_exp2f(s1[2]), __builtin_amdgcn_exp2f(s1[3]));
      o[qt][0] = __builtin_amdgcn_mfma_f32_16x16x32_bf16(pk.v, vf0, o[qt][0], 0, 0, 0);
      o[qt][1] = __builtin_amdgcn_mfma_f32_16x16x32_bf16(pk.v, vf1, o[qt][1], 0, 0, 0);
    }
    __builtin_amdgcn_s_setprio(0);
  };

  const bool interior = ((unsigned)(wy - 1) < 14u) && ((unsigned)(wx - 1) < 14u);

  if (interior) {
    // ---- interior: clamp-free byte-offset addressing, depth-2 pipeline ----
    unsigned koff[3][2], voff[3][2];
    #pragma unroll
    for (int cm = 0; cm < 3; ++cm) {
      #pragma unroll
      for (int j = 0; j < 2; ++j) {
        int pk = 32 * cm + key0 + 4 * j;
        int py = pk / 24, px = pk - py * 24;
        koff[cm][j] = (unsigned)((((ybase + py) * 256 + xbase + px) * 384) + (hc + quad * 8) * 2);
        int pv = 32 * cm + quad * 8 + 4 * j;
        int pyv = pv / 24, pxv = pv - pyv * 24;
        voff[cm][j] = (unsigned)((((ybase + pyv) * 256 + xbase + pxv) * 384) + (hc + l16) * 8);
      }
    }
    const char* kp = (const char*)k_tok;
    const char* vp = (const char*)vt4;
    auto lK = [&](int c, bf16x8* kf) {
      const int cm = c % 3; const unsigned cb = (unsigned)(c / 3) * 393216u;
      #pragma unroll
      for (int kt = 0; kt < 2; ++kt)
        kf[kt] = *reinterpret_cast<const bf16x8*>(kp + (size_t)(koff[cm][kt] + cb));
    };
    auto lV = [&](int c, uint2* va, uint2* vb) {
      const int cm = c % 3; const unsigned cb = (unsigned)(c / 3) * 393216u;
      #pragma unroll
      for (int h2 = 0; h2 < 2; ++h2) {
        const char* g = vp + (size_t)(voff[cm][h2] + cb);
        va[h2] = *reinterpret_cast<const uint2*>(g);        // dims l16
        vb[h2] = *reinterpret_cast<const uint2*>(g + 128);  // dims 16+l16
      }
    };
    bf16x8 kbuf[3][2]; uint2 vabuf[3][2], vbbuf[3][2];
    lK(0, kbuf[0]); lV(0, vabuf[0], vbbuf[0]);
    lK(1, kbuf[1]); lV(1, vabuf[1], vbbuf[1]);
    #pragma unroll
    for (int c = 0; c < 18; ++c) {
      const int cur = c % 3, nxt = (c + 2) % 3;   // literals after unroll
      if (c < 16) { lK(c + 2, kbuf[nxt]); lV(c + 2, vabuf[nxt], vbbuf[nxt]); }
      compute(kbuf[cur], vabuf[cur], vbbuf[cur]);
    }
  } else {
    // ---- border: clamped path, depth-1 ping-pong ----
    int kpy[3][2], ktx[3][2]; bool kxin[3][2];
    int vpy[3][2], vtx[3][2]; bool vxin[3][2];
    #pragma unroll
    for (int cm = 0; cm < 3; ++cm) {
      #pragma unroll
      for (int j = 0; j < 2; ++j) {
        int pk = 32 * cm + key0 + 4 * j;
        int py = pk / 24, px = pk - py * 24;
        kpy[cm][j] = py; ktx[cm][j] = xbase + px;
        kxin[cm][j] = (unsigned)(xbase + px) < 256u;
        int pv = 32 * cm + quad * 8 + 4 * j;
        int pyv = pv / 24, pxv = pv - pyv * 24;
        vpy[cm][j] = pyv; vtx[cm][j] = xbase + pxv;
        vxin[cm][j] = (unsigned)(xbase + pxv) < 256u;
      }
    }
    const int dOff0 = (hc + l16) * 4, dOff1 = (hc + 16 + l16) * 4;
    auto loadK = [&](int c, bf16x8* kf) {
      const int cm = c % 3, c3 = c / 3;
      const int yrow = ybase + 4 * c3;
      #pragma unroll
      for (int kt = 0; kt < 2; ++kt) {
        int y = yrow + kpy[cm][kt];
        bool inb = kxin[cm][kt] && ((unsigned)y < 256u);
        int t = inb ? (y * 256 + ktx[cm][kt]) : NTOK;
        kf[kt] = *reinterpret_cast<const bf16x8*>(k_tok + (size_t)t * CPAD + hc + quad * 8);
      }
    };
    auto loadV = [&](int c, uint2* va, uint2* vb) {
      const int cm = c % 3, c3 = c / 3;
      const int yrow = ybase + 4 * c3;
      #pragma unroll
      for (int h2 = 0; h2 < 2; ++h2) {
        int y = yrow + vpy[cm][h2];
        bool inb = vxin[cm][h2] && ((unsigned)y < 256u);
        int t = inb ? (y * 256 + vtx[cm][h2]) : NTOK;
        const ushort_t* gp = vt4 + (size_t)t * 192;
        va[h2] = *reinterpret_cast<const uint2*>(gp + dOff0);
        vb[h2] = *reinterpret_cast<const uint2*>(gp + dOff1);
      }
    };
    bf16x8 kbuf[2][2]; uint2 vabuf[2][2], vbbuf[2][2];
    loadK(0, kbuf[0]); loadV(0, vabuf[0], vbbuf[0]);
    #pragma unroll
    for (int c = 0; c < 18; ++c) {
      const int cur = c & 1, nxt = cur ^ 1;
      if (c < 17) { loadK(c + 1, kbuf[nxt]); loadV(c + 1, vabuf[nxt], vbbuf[nxt]); }
      compute(kbuf[cur], vabuf[cur], vbbuf[cur]);
    }
  }

  // ---- epilogue: l = O[:,30] (ones-column), O /= l, scatter
  #pragma unroll
  for (int qt = 0; qt < 4; ++qt) {
    #pragma unroll
    for (int r = 0; r < 4; ++r) {
      float l = __shfl(o[qt][1][r], (lane & 48) + 14, 64);
      float inv = 1.0f / l;
      int qi = wave * 64 + qt * 16 + quad * 4 + r;
      int token = tok0 + (qi >> 4) * 256 + (qi & 15);
      ao[(size_t)token * CPAD + hc + l16]      = f2bf(o[qt][0][r] * inv);
      ao[(size_t)token * CPAD + hc + 16 + l16] = f2bf(o[qt][1][r] * inv);
    }
  }
}

// ---------------- launch ----------------
extern "C" void kernel_launch(void* const* d_in, const int* in_sizes, int n_in,
                              void* d_out, int out_size, void* d_ws, size_t ws_size,
                              hipStream_t stream) {
  const float* x      = (const float*)d_in[0];
  const float* norm_w = (const float*)d_in[1];
  const float* norm_b = (const float*)d_in[2];
  const float* q_w    = (const float*)d_in[3];
  const float* q_b    = (const float*)d_in[4];
  const float* kv_w   = (const float*)d_in[5];
  const float* kv_b   = (const float*)d_in[6];
  const float* p_w    = (const float*)d_in[7];
  const float* p_b    = (const float*)d_in[8];

  char* base = (char*)d_ws;
  size_t off = 0;
  auto alloc = [&](size_t bytes) { char* p = base + off; off = (off + bytes + 255) & ~(size_t)255; return p; };
  ushort_t* ao    = (ushort_t*)alloc((size_t)NTOK * CPAD * 2);
  ushort_t* q_tok = (ushort_t*)alloc((size_t)NTOK * CPAD * 2);
  ushort_t* k_tok = (ushort_t*)alloc((size_t)(NTOK + 1) * CPAD * 2);  // +1 bias row
  ushort_t* vt4   = (ushort_t*)alloc((size_t)(NTOK + 4) * 192 * 2);   // +1 bias group
  ushort_t* wqkvt = (ushort_t*)alloc(576 * 192 * 2);
  ushort_t* pwt   = (ushort_t*)alloc(192 * 192 * 2);
  float* qkvb = (float*)alloc(576 * 4);
  float* pbp  = (float*)alloc(192 * 4);

  prep_k<<<583, 256, 0, stream>>>(q_w, q_b, kv_w, kv_b, p_w, p_b,
                                  wqkvt, pwt, qkvb, pbp,
                                  k_tok + (size_t)NTOK * CPAD,
                                  vt4 + (size_t)NTOK * 192);
  // LN fused into gemm_k<0> staging; BM=128, grid 512; W2 B-layout
  gemm_k<0><<<NTOK / 128, 256, 0, stream>>>(nullptr, x, norm_w, norm_b,
                                            wqkvt, qkvb, q_tok, k_tok, vt4, nullptr, nullptr);
  // attn: 1-wave blocks (grid 256x6x4, 64 threads)
  attn_k<<<dim3(256, 6, 4), 64, 0, stream>>>(q_tok, k_tok, vt4, ao);
  gemm_k<1><<<NTOK / 128, 256, 0, stream>>>(ao, nullptr, nullptr, nullptr,
                                            pwt, pbp, nullptr, nullptr, nullptr, (float*)d_out, x);
}

// Round 12
// 228.606 us; speedup vs baseline: 2.0519x; 2.0519x over previous
//
#include <hip/hip_runtime.h>
#include <math.h>

typedef __bf16 bf16x8 __attribute__((ext_vector_type(8)));
typedef float f32x4 __attribute__((ext_vector_type(4)));
typedef unsigned short ushort_t;

static __device__ __forceinline__ unsigned short f2bf(float f) {
  union { float f; unsigned int u; } c; c.f = f;
  unsigned int u = c.u;
  unsigned int r = u + 0x7FFFu + ((u >> 16) & 1u);
  return (unsigned short)(r >> 16);
}

// ---------------- constants ----------------
#define CDIM 180      // true channel dim
#define CPAD 192      // padded: 6 heads * 32
#define NTOK 65536

// scale * log2(e), folded into Q weights/bias at prep: p = exp2(S)
#define SCL2E 0.26339361f

// pack two f32's high halves into packed bf16 pair (truncating): D = {hi16(b), hi16(a)}
static __device__ __forceinline__ unsigned pk_bf(float a, float b) {
  union { float f; unsigned u; } ca, cb; ca.f = a; cb.f = b;
  return __builtin_amdgcn_perm(cb.u, ca.u, 0x07060302u);
}

// ---------------- prep ----------------
// Wt stored in WAVE-COALESCED W2 layout (round-9/10: n-major [n][k] made
// every gemm B-load a 16-segment gather; request count was the bottleneck).
// W2 chunk = (((tile*2+wn)*2+nt)*6+ks)*512 + lane*8 ushorts: one wave's
// B-fragment load = 1024 contiguous bytes.
//   wqkvt: 9 tiles (n<192: Q *SCL2E; 192..383: K; 384..575: V), 110592 elems
//   pwt:   3 tiles, 36864 elems
// qkvb[576] (Q part *SCL2E), pbp[192], k_bias_row[192] (-> k_tok row NTOK),
// vt4 bias group (tok NTOK).
__global__ __launch_bounds__(256) void prep_k(
    const float* __restrict__ q_w, const float* __restrict__ q_b,
    const float* __restrict__ kv_w, const float* __restrict__ kv_b,
    const float* __restrict__ p_w, const float* __restrict__ p_b,
    ushort_t* __restrict__ wqkvt, ushort_t* __restrict__ pwt,
    float* __restrict__ qkvb, float* __restrict__ pbp,
    ushort_t* __restrict__ k_bias_row, ushort_t* __restrict__ vt4_bias_grp)
{
  int i = blockIdx.x * 256 + threadIdx.x;
  if (i < 110592) { // wqkvt, W2 layout
    int r = i & 7, i8 = i >> 3;
    int lane = i8 & 63, t1 = i8 >> 6;
    int ks = t1 % 6, t2 = t1 / 6;
    int nt = t2 & 1, wn = (t2 >> 1) & 1, tile = t2 >> 2;
    int n = tile * 64 + wn * 32 + nt * 16 + (lane & 15);
    int k = ks * 32 + (lane >> 4) * 8 + r;
    float v = 0.f;
    if (k < CDIM) {
      if (n < 192) { int h = n >> 5, d = n & 31; if (d < 30) v = q_w[k * CDIM + h * 30 + d] * SCL2E; }
      else { int cn = n - 192; int part = cn >= 192; int c2 = cn - part * 192;
             int h = c2 >> 5, d = c2 & 31;
             if (d < 30) v = kv_w[k * 360 + part * 180 + h * 30 + d]; }
    }
    wqkvt[i] = f2bf(v);
    return;
  }
  i -= 110592;
  if (i < 36864) { // pwt, W2 layout (3 tiles)
    int r = i & 7, i8 = i >> 3;
    int lane = i8 & 63, t1 = i8 >> 6;
    int ks = t1 % 6, t2 = t1 / 6;
    int nt = t2 & 1, wn = (t2 >> 1) & 1, tile = t2 >> 2;
    int n = tile * 64 + wn * 32 + nt * 16 + (lane & 15);
    int k = ks * 32 + (lane >> 4) * 8 + r;
    int h = k >> 5, d = k & 31;
    float v = (d < 30 && n < CDIM) ? p_w[(h * 30 + d) * CDIM + n] : 0.f;
    pwt[i] = f2bf(v);
    return;
  }
  i -= 36864;
  if (i < 576) {
    float v = 0.f;
    if (i < 192) { int h = i >> 5, d = i & 31; if (d < 30) v = q_b[h * 30 + d] * SCL2E; }
    else { int cn = i - 192; int part = cn >= 192; int c2 = cn - part * 192;
           int h = c2 >> 5, d = c2 & 31;
           if (d < 30) v = kv_b[part * 180 + h * 30 + d];
           else if (part == 1 && d == 30) v = 1.0f; }  // ones-column -> row-sum l
    qkvb[i] = v;
    return;
  }
  i -= 576;
  if (i < 192) { pbp[i] = (i < CDIM) ? p_b[i] : 0.f; return; }
  i -= 192;
  if (i < 192) { // K bias row (zero-padded positions: xn==0 -> k = bias)
    int h = i >> 5, d = i & 31;
    k_bias_row[i] = (d < 30) ? f2bf(kv_b[h * 30 + d]) : (ushort_t)0;
    return;
  }
  i -= 192;
  if (i < 768) { // vt4 bias group at tok==NTOK: [192 d][4]
    int d = i >> 2, h = d >> 5, dd = d & 31;
    float v = 0.f;
    if (dd < 30) v = kv_b[180 + h * 30 + dd];
    else if (dd == 30) v = 1.0f;
    vt4_bias_grp[i] = f2bf(v);
    return;
  }
}

// ---------------- fused GEMM: BM=128, coalesced W2 B-loads ----------
// B-load per wave = 1024B contiguous (W2 layout) -> single-segment stream.
// Depth-2 register pipeline on B.
// MODE 0: A-tile built by FUSED LAYERNORM from x f32 (16-lane-group LN,
//         f2bf rounding matches old ln_k exactly). 9 n-tiles:
//         n<192 -> q_tok; 192..383 -> k_tok; 384..575 -> vt4.
// MODE 1: A=ao (bf16), Wt=pwt, 3 n-tiles: d_out f32 + residual x
template<int MODE>
__global__ __launch_bounds__(256) void gemm_k(const ushort_t* __restrict__ A,
    const float* __restrict__ x, const float* __restrict__ nw, const float* __restrict__ nb,
    const ushort_t* __restrict__ Wt, const float* __restrict__ bias,
    ushort_t* __restrict__ q_out, ushort_t* __restrict__ k_out,
    ushort_t* __restrict__ vt_out,
    float* __restrict__ outf, const float* __restrict__ resid)
{
  constexpr int NT = (MODE == 0) ? 9 : 3;
  __shared__ __align__(16) ushort_t aS[128 * 200];
  const int tid = threadIdx.x;
  const int lane = tid & 63, wave = tid >> 6;
  const int quad = lane >> 4, l16 = lane & 15;
  const int wm = wave & 1, wn = wave >> 1;
  const int bm = blockIdx.x;

  if constexpr (MODE == 0) {
    // ---- fused LayerNorm staging: 128 rows of x[.][180] f32 -> bf16 aS ----
    const float* xb = x + (size_t)bm * 128 * CDIM;
    const int grp = tid >> 4, gl = tid & 15;
    float wv[12], bvv[12];
    if (gl < 15) {
      #pragma unroll
      for (int e = 0; e < 3; ++e) {
        float4 w4 = *reinterpret_cast<const float4*>(nw + gl * 12 + e * 4);
        float4 b4 = *reinterpret_cast<const float4*>(nb + gl * 12 + e * 4);
        wv[e*4+0] = w4.x; wv[e*4+1] = w4.y; wv[e*4+2] = w4.z; wv[e*4+3] = w4.w;
        bvv[e*4+0] = b4.x; bvv[e*4+1] = b4.y; bvv[e*4+2] = b4.z; bvv[e*4+3] = b4.w;
      }
    } else {
      #pragma unroll
      for (int k = 0; k < 12; ++k) { wv[k] = 0.f; bvv[k] = 0.f; }
    }
    #pragma unroll 2
    for (int i = 0; i < 8; ++i) {
      const int row = i * 16 + grp;
      const float* xr = xb + (size_t)row * CDIM;
      float v[12];
      float sum = 0.f, sq = 0.f;
      if (gl < 15) {
        #pragma unroll
        for (int e = 0; e < 3; ++e) {
          float4 x4 = *reinterpret_cast<const float4*>(xr + gl * 12 + e * 4);
          v[e*4+0] = x4.x; v[e*4+1] = x4.y; v[e*4+2] = x4.z; v[e*4+3] = x4.w;
        }
        #pragma unroll
        for (int k = 0; k < 12; ++k) { sum += v[k]; sq += v[k] * v[k]; }
      } else {
        #pragma unroll
        for (int k = 0; k < 12; ++k) v[k] = 0.f;
      }
      #pragma unroll
      for (int off = 1; off < 16; off <<= 1) {
        sum += __shfl_xor(sum, off, 64);
        sq  += __shfl_xor(sq, off, 64);
      }
      const float inv_n = 1.0f / 180.0f;
      float mean = sum * inv_n;
      float var = sq * inv_n - mean * mean;
      float rs = rsqrtf(var + 1e-5f);
      unsigned u[6];
      #pragma unroll
      for (int p = 0; p < 6; ++p) {
        float a = (v[2*p]   - mean) * rs * wv[2*p]   + bvv[2*p];
        float b = (v[2*p+1] - mean) * rs * wv[2*p+1] + bvv[2*p+1];
        u[p] = (unsigned)f2bf(a) | ((unsigned)f2bf(b) << 16);
      }
      ushort_t* dst = &aS[row * 200 + gl * 12];
      uint2 w01; w01.x = u[0]; w01.y = u[1];
      uint2 w23; w23.x = u[2]; w23.y = u[3];
      uint2 w45; w45.x = u[4]; w45.y = u[5];
      *reinterpret_cast<uint2*>(dst)     = w01;
      *reinterpret_cast<uint2*>(dst + 4) = w23;
      *reinterpret_cast<uint2*>(dst + 8) = w45;
    }
  } else {
    // stage full A tile: 128 rows x 192 cols (bf16 input)
    const ushort_t* Ab = A + (size_t)bm * 128 * 192;
    #pragma unroll
    for (int it = 0; it < 12; ++it) {
      int f = it * 256 + tid;
      int row = f / 24, kq = f % 24;
      uint4 v = *reinterpret_cast<const uint4*>(Ab + row * 192 + kq * 8);
      *reinterpret_cast<uint4*>(&aS[row * 200 + kq * 8]) = v;
    }
  }
  __syncthreads();  // the only barrier

  // W2 B-load: chunk (((tile*2+wn)*2+nt)*6+ks)*512 + lane*8; nt stride 3072
  auto ldB = [&](int tile, int ks, bf16x8* dst) {
    const ushort_t* p = Wt + (size_t)((tile * 2 + wn) * 12 + ks) * 512 + lane * 8;
    dst[0] = *reinterpret_cast<const bf16x8*>(p);
    dst[1] = *reinterpret_cast<const bf16x8*>(p + 3072);
  };

  bf16x8 bB0[2], bB1[2], bB2[2];
  ldB(0, 0, bB0);
  ldB(0, 1, bB1);

  for (int nt0 = 0; nt0 < NT; ++nt0) {
    const int ntn = (nt0 + 1 < NT) ? nt0 + 1 : 0;   // wrap: harmless redundant loads
    f32x4 acc[4][2] = {};

    // step KS: prefetch (PT,PKS) into PRE, compute with CUR
    #define GSTEP(KS, CUR, PRE, PT, PKS) do { \
      ldB(PT, PKS, PRE); \
      bf16x8 af[4]; \
      _Pragma("unroll") \
      for (int mt = 0; mt < 4; ++mt) \
        af[mt] = *reinterpret_cast<const bf16x8*>(&aS[(wm * 64 + mt * 16 + l16) * 200 + KS * 32 + quad * 8]); \
      _Pragma("unroll") \
      for (int mt = 0; mt < 4; ++mt) { \
        acc[mt][0] = __builtin_amdgcn_mfma_f32_16x16x32_bf16(af[mt], CUR[0], acc[mt][0], 0, 0, 0); \
        acc[mt][1] = __builtin_amdgcn_mfma_f32_16x16x32_bf16(af[mt], CUR[1], acc[mt][1], 0, 0, 0); \
      } \
    } while (0)

    GSTEP(0, bB0, bB2, nt0, 2);
    GSTEP(1, bB1, bB0, nt0, 3);
    GSTEP(2, bB2, bB1, nt0, 4);
    GSTEP(3, bB0, bB2, nt0, 5);
    GSTEP(4, bB1, bB0, ntn, 0);
    GSTEP(5, bB2, bB1, ntn, 1);
    #undef GSTEP

    // epilogue for this n-tile (also covers the cross-tile prefetches)
    #pragma unroll
    for (int mt = 0; mt < 4; ++mt) {
      int row = bm * 128 + wm * 64 + mt * 16 + quad * 4;
      #pragma unroll
      for (int nt = 0; nt < 2; ++nt) {
        int ncol = nt0 * 64 + wn * 32 + nt * 16 + l16;
        float bv = bias[ncol];
        if (MODE == 0 && nt0 >= 6) {
          // V part: 4 consecutive tokens (row..row+3, row%4==0) for dim d
          int d = ncol - 384;
          unsigned p0 = pk_bf(acc[mt][nt][0] + bv, acc[mt][nt][1] + bv);
          unsigned p1 = pk_bf(acc[mt][nt][2] + bv, acc[mt][nt][3] + bv);
          uint2 val; val.x = p0; val.y = p1;
          // vt4 index = tok*192 rearranged: (tok>>2)*768 + d*4 + (tok&3)
          *reinterpret_cast<uint2*>(vt_out + (size_t)row * 192 + d * 4) = val;
        } else {
          #pragma unroll
          for (int r = 0; r < 4; ++r) {
            int rr = row + r;
            float v = acc[mt][nt][r] + bv;
            if (MODE == 0) {
              if (ncol < 192) q_out[(size_t)rr * CPAD + ncol] = f2bf(v);
              else k_out[(size_t)rr * CPAD + (ncol - 192)] = f2bf(v);
            } else {
              if (ncol < CDIM) outf[(size_t)rr * CDIM + ncol] = v + resid[(size_t)rr * CDIM + ncol];
            }
          }
        }
      }
    }
  }
}

// ---------------- attention: 1-wave blocks, FULL register cap (round-12) ---
// Round-11's launch_bounds(64,6) capped VGPR at ~85 < the ~110 live set ->
// catastrophic scratch spill (WRITE 28.5->652 MB). This round: identical
// body, launch_bounds(64,4) -> cap 128, same as the proven 4-wave config
// (which compiled to VGPR=64, zero spill). Isolates the one variable:
// scheduling granularity (6144 1-wave blocks vs 1536 4-wave blocks).
// S^T = K·Q^T; C-layout of S^T == A-layout of PV MFMA under key permutation
// key(kt,m) = 8*(m>>2) + 4*kt + (m&3). V in group-of-4 layout vt4; OOB ->
// bias group/row at tok NTOK. Fixed-max softmax (Q pre-scaled); l via V
// ones-column (d30). Interior: clamp-free offsets, depth-2 pipeline.
// Border: clamped depth-1 ping-pong.
__global__ __launch_bounds__(64, 4) void attn_k(const ushort_t* __restrict__ q_tok,
    const ushort_t* __restrict__ k_tok, const ushort_t* __restrict__ vt4,
    ushort_t* __restrict__ ao)
{
  const int w = blockIdx.x, h = blockIdx.y;
  const int wave = blockIdx.z;
  const int lane = threadIdx.x & 63;
  const int quad = lane >> 4, l16 = lane & 15;
  const int wy = w >> 4, wx = w & 15;
  const int tok0 = wy * 16 * 256 + wx * 16;
  const int hc = h * 32;
  const int ybase = wy * 16 - 4, xbase = wx * 16 - 4;

  // Q fragments (B-operand layout), 4 q-tiles of 16
  bf16x8 qf[4];
  #pragma unroll
  for (int qt = 0; qt < 4; ++qt) {
    int qi = wave * 64 + qt * 16 + l16;
    int token = tok0 + (qi >> 4) * 256 + (qi & 15);
    qf[qt] = *reinterpret_cast<const bf16x8*>(q_tok + (size_t)token * CPAD + hc + quad * 8);
  }

  // permuted key id for the K A-frag gather
  const int key0 = ((l16 >> 2) << 3) + (l16 & 3);

  f32x4 o[4][2] = {};
  f32x4 zero = {0.f, 0.f, 0.f, 0.f};

  // shared compute step: S^T = K Q^T (pre-scaled), raw v_exp, pack P, PV
  auto compute = [&](const bf16x8* kf, const uint2* va, const uint2* vb) {
    bf16x8 vf0, vf1;
    {
      union { unsigned u[4]; bf16x8 v; } a_;
      a_.u[0] = va[0].x; a_.u[1] = va[0].y; a_.u[2] = va[1].x; a_.u[3] = va[1].y;
      vf0 = a_.v;
      a_.u[0] = vb[0].x; a_.u[1] = vb[0].y; a_.u[2] = vb[1].x; a_.u[3] = vb[1].y;
      vf1 = a_.v;
    }
    __builtin_amdgcn_s_setprio(1);
    #pragma unroll
    for (int qt = 0; qt < 4; ++qt) {
      f32x4 s0 = __builtin_amdgcn_mfma_f32_16x16x32_bf16(kf[0], qf[qt], zero, 0, 0, 0);
      f32x4 s1 = __builtin_amdgcn_mfma_f32_16x16x32_bf16(kf[1], qf[qt], zero, 0, 0, 0);
      union { unsigned u[4]; bf16x8 v; } pk;
      pk.u[0] = pk_bf(__builtin_amdgcn_exp2f(s0[0]), __builtin_amdgcn_exp2f(s0[1]));
      pk.u[1] = pk_bf(__builtin_amdgcn_exp2f(s0[2]), __builtin_amdgcn_exp2f(s0[3]));
      pk.u[2] = pk_bf(__builtin_amdgcn_exp2f(s1[0]), __builtin_amdgcn_exp2f(s1[1]));
      pk.u[3] = pk_bf(__builtin_amdgcn_exp2f(s1[2]), __builtin_amdgcn_exp2f(s1[3]));
      o[qt][0] = __builtin_amdgcn_mfma_f32_16x16x32_bf16(pk.v, vf0, o[qt][0], 0, 0, 0);
      o[qt][1] = __builtin_amdgcn_mfma_f32_16x16x32_bf16(pk.v, vf1, o[qt][1], 0, 0, 0);
    }
    __builtin_amdgcn_s_setprio(0);
  };

  const bool interior = ((unsigned)(wy - 1) < 14u) && ((unsigned)(wx - 1) < 14u);

  if (interior) {
    // ---- interior: clamp-free byte-offset addressing, depth-2 pipeline ----
    unsigned koff[3][2], voff[3][2];
    #pragma unroll
    for (int cm = 0; cm < 3; ++cm) {
      #pragma unroll
      for (int j = 0; j < 2; ++j) {
        int pk = 32 * cm + key0 + 4 * j;
        int py = pk / 24, px = pk - py * 24;
        koff[cm][j] = (unsigned)((((ybase + py) * 256 + xbase + px) * 384) + (hc + quad * 8) * 2);
        int pv = 32 * cm + quad * 8 + 4 * j;
        int pyv = pv / 24, pxv = pv - pyv * 24;
        voff[cm][j] = (unsigned)((((ybase + pyv) * 256 + xbase + pxv) * 384) + (hc + l16) * 8);
      }
    }
    const char* kp = (const char*)k_tok;
    const char* vp = (const char*)vt4;
    auto lK = [&](int c, bf16x8* kf) {
      const int cm = c % 3; const unsigned cb = (unsigned)(c / 3) * 393216u;
      #pragma unroll
      for (int kt = 0; kt < 2; ++kt)
        kf[kt] = *reinterpret_cast<const bf16x8*>(kp + (size_t)(koff[cm][kt] + cb));
    };
    auto lV = [&](int c, uint2* va, uint2* vb) {
      const int cm = c % 3; const unsigned cb = (unsigned)(c / 3) * 393216u;
      #pragma unroll
      for (int h2 = 0; h2 < 2; ++h2) {
        const char* g = vp + (size_t)(voff[cm][h2] + cb);
        va[h2] = *reinterpret_cast<const uint2*>(g);        // dims l16
        vb[h2] = *reinterpret_cast<const uint2*>(g + 128);  // dims 16+l16
      }
    };
    bf16x8 kbuf[3][2]; uint2 vabuf[3][2], vbbuf[3][2];
    lK(0, kbuf[0]); lV(0, vabuf[0], vbbuf[0]);
    lK(1, kbuf[1]); lV(1, vabuf[1], vbbuf[1]);
    #pragma unroll
    for (int c = 0; c < 18; ++c) {
      const int cur = c % 3, nxt = (c + 2) % 3;   // literals after unroll
      if (c < 16) { lK(c + 2, kbuf[nxt]); lV(c + 2, vabuf[nxt], vbbuf[nxt]); }
      compute(kbuf[cur], vabuf[cur], vbbuf[cur]);
    }
  } else {
    // ---- border: clamped path, depth-1 ping-pong ----
    int kpy[3][2], ktx[3][2]; bool kxin[3][2];
    int vpy[3][2], vtx[3][2]; bool vxin[3][2];
    #pragma unroll
    for (int cm = 0; cm < 3; ++cm) {
      #pragma unroll
      for (int j = 0; j < 2; ++j) {
        int pk = 32 * cm + key0 + 4 * j;
        int py = pk / 24, px = pk - py * 24;
        kpy[cm][j] = py; ktx[cm][j] = xbase + px;
        kxin[cm][j] = (unsigned)(xbase + px) < 256u;
        int pv = 32 * cm + quad * 8 + 4 * j;
        int pyv = pv / 24, pxv = pv - pyv * 24;
        vpy[cm][j] = pyv; vtx[cm][j] = xbase + pxv;
        vxin[cm][j] = (unsigned)(xbase + pxv) < 256u;
      }
    }
    const int dOff0 = (hc + l16) * 4, dOff1 = (hc + 16 + l16) * 4;
    auto loadK = [&](int c, bf16x8* kf) {
      const int cm = c % 3, c3 = c / 3;
      const int yrow = ybase + 4 * c3;
      #pragma unroll
      for (int kt = 0; kt < 2; ++kt) {
        int y = yrow + kpy[cm][kt];
        bool inb = kxin[cm][kt] && ((unsigned)y < 256u);
        int t = inb ? (y * 256 + ktx[cm][kt]) : NTOK;
        kf[kt] = *reinterpret_cast<const bf16x8*>(k_tok + (size_t)t * CPAD + hc + quad * 8);
      }
    };
    auto loadV = [&](int c, uint2* va, uint2* vb) {
      const int cm = c % 3, c3 = c / 3;
      const int yrow = ybase + 4 * c3;
      #pragma unroll
      for (int h2 = 0; h2 < 2; ++h2) {
        int y = yrow + vpy[cm][h2];
        bool inb = vxin[cm][h2] && ((unsigned)y < 256u);
        int t = inb ? (y * 256 + vtx[cm][h2]) : NTOK;
        const ushort_t* gp = vt4 + (size_t)t * 192;
        va[h2] = *reinterpret_cast<const uint2*>(gp + dOff0);
        vb[h2] = *reinterpret_cast<const uint2*>(gp + dOff1);
      }
    };
    bf16x8 kbuf[2][2]; uint2 vabuf[2][2], vbbuf[2][2];
    loadK(0, kbuf[0]); loadV(0, vabuf[0], vbbuf[0]);
    #pragma unroll
    for (int c = 0; c < 18; ++c) {
      const int cur = c & 1, nxt = cur ^ 1;
      if (c < 17) { loadK(c + 1, kbuf[nxt]); loadV(c + 1, vabuf[nxt], vbbuf[nxt]); }
      compute(kbuf[cur], vabuf[cur], vbbuf[cur]);
    }
  }

  // ---- epilogue: l = O[:,30] (ones-column), O /= l, scatter
  #pragma unroll
  for (int qt = 0; qt < 4; ++qt) {
    #pragma unroll
    for (int r = 0; r < 4; ++r) {
      float l = __shfl(o[qt][1][r], (lane & 48) + 14, 64);
      float inv = 1.0f / l;
      int qi = wave * 64 + qt * 16 + quad * 4 + r;
      int token = tok0 + (qi >> 4) * 256 + (qi & 15);
      ao[(size_t)token * CPAD + hc + l16]      = f2bf(o[qt][0][r] * inv);
      ao[(size_t)token * CPAD + hc + 16 + l16] = f2bf(o[qt][1][r] * inv);
    }
  }
}

// ---------------- launch ----------------
extern "C" void kernel_launch(void* const* d_in, const int* in_sizes, int n_in,
                              void* d_out, int out_size, void* d_ws, size_t ws_size,
                              hipStream_t stream) {
  const float* x      = (const float*)d_in[0];
  const float* norm_w = (const float*)d_in[1];
  const float* norm_b = (const float*)d_in[2];
  const float* q_w    = (const float*)d_in[3];
  const float* q_b    = (const float*)d_in[4];
  const float* kv_w   = (const float*)d_in[5];
  const float* kv_b   = (const float*)d_in[6];
  const float* p_w    = (const float*)d_in[7];
  const float* p_b    = (const float*)d_in[8];

  char* base = (char*)d_ws;
  size_t off = 0;
  auto alloc = [&](size_t bytes) { char* p = base + off; off = (off + bytes + 255) & ~(size_t)255; return p; };
  ushort_t* ao    = (ushort_t*)alloc((size_t)NTOK * CPAD * 2);
  ushort_t* q_tok = (ushort_t*)alloc((size_t)NTOK * CPAD * 2);
  ushort_t* k_tok = (ushort_t*)alloc((size_t)(NTOK + 1) * CPAD * 2);  // +1 bias row
  ushort_t* vt4   = (ushort_t*)alloc((size_t)(NTOK + 4) * 192 * 2);   // +1 bias group
  ushort_t* wqkvt = (ushort_t*)alloc(576 * 192 * 2);
  ushort_t* pwt   = (ushort_t*)alloc(192 * 192 * 2);
  float* qkvb = (float*)alloc(576 * 4);
  float* pbp  = (float*)alloc(192 * 4);

  prep_k<<<583, 256, 0, stream>>>(q_w, q_b, kv_w, kv_b, p_w, p_b,
                                  wqkvt, pwt, qkvb, pbp,
                                  k_tok + (size_t)NTOK * CPAD,
                                  vt4 + (size_t)NTOK * 192);
  // LN fused into gemm_k<0> staging; BM=128, grid 512; W2 B-layout
  gemm_k<0><<<NTOK / 128, 256, 0, stream>>>(nullptr, x, norm_w, norm_b,
                                            wqkvt, qkvb, q_tok, k_tok, vt4, nullptr, nullptr);
  // attn: 1-wave blocks (grid 256x6x4, 64 threads), full 128-reg cap
  attn_k<<<dim3(256, 6, 4), 64, 0, stream>>>(q_tok, k_tok, vt4, ao);
  gemm_k<1><<<NTOK / 128, 256, 0, stream>>>(ao, nullptr, nullptr, nullptr,
                                            pwt, pbp, nullptr, nullptr, nullptr, (float*)d_out, x);
}

// Round 13
// 207.758 us; speedup vs baseline: 2.2578x; 1.1003x over previous
//
#include <hip/hip_runtime.h>
#include <math.h>

typedef __bf16 bf16x8 __attribute__((ext_vector_type(8)));
typedef float f32x4 __attribute__((ext_vector_type(4)));
typedef unsigned short ushort_t;

static __device__ __forceinline__ unsigned short f2bf(float f) {
  union { float f; unsigned int u; } c; c.f = f;
  unsigned int u = c.u;
  unsigned int r = u + 0x7FFFu + ((u >> 16) & 1u);
  return (unsigned short)(r >> 16);
}

// ---------------- constants ----------------
#define CDIM 180      // true channel dim
#define CPAD 192      // padded: 6 heads * 32
#define NTOK 65536

// scale * log2(e), folded into Q weights/bias at prep: p = exp2(S)
#define SCL2E 0.26339361f

// pack two f32's high halves into packed bf16 pair (truncating): D = {hi16(b), hi16(a)}
static __device__ __forceinline__ unsigned pk_bf(float a, float b) {
  union { float f; unsigned u; } ca, cb; ca.f = a; cb.f = b;
  return __builtin_amdgcn_perm(cb.u, ca.u, 0x07060302u);
}

// ---------------- prep ----------------
// Wt stored in WAVE-COALESCED W2 layout (round-9/10: n-major [n][k] made
// every gemm B-load a 16-segment gather; request count was the bottleneck).
// W2 chunk = (((tile*2+wn)*2+nt)*6+ks)*512 + lane*8 ushorts: one wave's
// B-fragment load = 1024 contiguous bytes.
//   wqkvt: 9 tiles (n<192: Q *SCL2E; 192..383: K; 384..575: V), 110592 elems
//   pwt:   3 tiles, 36864 elems
// qkvb[576] (Q part *SCL2E), pbp[192], k_bias_row[192] (-> k_tok row NTOK),
// vt4 bias group (tok NTOK).
__global__ __launch_bounds__(256) void prep_k(
    const float* __restrict__ q_w, const float* __restrict__ q_b,
    const float* __restrict__ kv_w, const float* __restrict__ kv_b,
    const float* __restrict__ p_w, const float* __restrict__ p_b,
    ushort_t* __restrict__ wqkvt, ushort_t* __restrict__ pwt,
    float* __restrict__ qkvb, float* __restrict__ pbp,
    ushort_t* __restrict__ k_bias_row, ushort_t* __restrict__ vt4_bias_grp)
{
  int i = blockIdx.x * 256 + threadIdx.x;
  if (i < 110592) { // wqkvt, W2 layout
    int r = i & 7, i8 = i >> 3;
    int lane = i8 & 63, t1 = i8 >> 6;
    int ks = t1 % 6, t2 = t1 / 6;
    int nt = t2 & 1, wn = (t2 >> 1) & 1, tile = t2 >> 2;
    int n = tile * 64 + wn * 32 + nt * 16 + (lane & 15);
    int k = ks * 32 + (lane >> 4) * 8 + r;
    float v = 0.f;
    if (k < CDIM) {
      if (n < 192) { int h = n >> 5, d = n & 31; if (d < 30) v = q_w[k * CDIM + h * 30 + d] * SCL2E; }
      else { int cn = n - 192; int part = cn >= 192; int c2 = cn - part * 192;
             int h = c2 >> 5, d = c2 & 31;
             if (d < 30) v = kv_w[k * 360 + part * 180 + h * 30 + d]; }
    }
    wqkvt[i] = f2bf(v);
    return;
  }
  i -= 110592;
  if (i < 36864) { // pwt, W2 layout (3 tiles)
    int r = i & 7, i8 = i >> 3;
    int lane = i8 & 63, t1 = i8 >> 6;
    int ks = t1 % 6, t2 = t1 / 6;
    int nt = t2 & 1, wn = (t2 >> 1) & 1, tile = t2 >> 2;
    int n = tile * 64 + wn * 32 + nt * 16 + (lane & 15);
    int k = ks * 32 + (lane >> 4) * 8 + r;
    int h = k >> 5, d = k & 31;
    float v = (d < 30 && n < CDIM) ? p_w[(h * 30 + d) * CDIM + n] : 0.f;
    pwt[i] = f2bf(v);
    return;
  }
  i -= 36864;
  if (i < 576) {
    float v = 0.f;
    if (i < 192) { int h = i >> 5, d = i & 31; if (d < 30) v = q_b[h * 30 + d] * SCL2E; }
    else { int cn = i - 192; int part = cn >= 192; int c2 = cn - part * 192;
           int h = c2 >> 5, d = c2 & 31;
           if (d < 30) v = kv_b[part * 180 + h * 30 + d];
           else if (part == 1 && d == 30) v = 1.0f; }  // ones-column -> row-sum l
    qkvb[i] = v;
    return;
  }
  i -= 576;
  if (i < 192) { pbp[i] = (i < CDIM) ? p_b[i] : 0.f; return; }
  i -= 192;
  if (i < 192) { // K bias row (zero-padded positions: xn==0 -> k = bias)
    int h = i >> 5, d = i & 31;
    k_bias_row[i] = (d < 30) ? f2bf(kv_b[h * 30 + d]) : (ushort_t)0;
    return;
  }
  i -= 192;
  if (i < 768) { // vt4 bias group at tok==NTOK: [192 d][4]
    int d = i >> 2, h = d >> 5, dd = d & 31;
    float v = 0.f;
    if (dd < 30) v = kv_b[180 + h * 30 + dd];
    else if (dd == 30) v = 1.0f;
    vt4_bias_grp[i] = f2bf(v);
    return;
  }
}

// ---------------- fused GEMM: BM=128, W2 B-loads, LDS-transposed q/k store -
// Round-8 established gemm time tracks memory REQUEST count. Post-W2 the
// dominant fragmented stream is the q/k epilogue: 192 insts/wave of 2B/lane
// (4x32B segments each, ~1.57M segments for 50MB). Fix: per q/k n-tile,
// deposit the C-tile into an 18KB LDS buffer (stride 72 ushorts: rows
// 16B-aligned), barrier, then re-read row-major and store 16B/lane ->
// 128B contiguous segments (8/inst), ~0.39M segments total (4x fewer).
// V path (nt0>=6) already writes 128B segments - unchanged.
// MODE 0: A-tile built by FUSED LAYERNORM from x f32 (16-lane-group LN,
//         f2bf rounding matches old ln_k exactly). 9 n-tiles:
//         n<192 -> q_tok; 192..383 -> k_tok; 384..575 -> vt4.
// MODE 1: A=ao (bf16), Wt=pwt, 3 n-tiles: d_out f32 + residual x
template<int MODE>
__global__ __launch_bounds__(256) void gemm_k(const ushort_t* __restrict__ A,
    const float* __restrict__ x, const float* __restrict__ nw, const float* __restrict__ nb,
    const ushort_t* __restrict__ Wt, const float* __restrict__ bias,
    ushort_t* __restrict__ q_out, ushort_t* __restrict__ k_out,
    ushort_t* __restrict__ vt_out,
    float* __restrict__ outf, const float* __restrict__ resid)
{
  constexpr int NT = (MODE == 0) ? 9 : 3;
  __shared__ __align__(16) ushort_t aS[128 * 200];
  __shared__ __align__(16) ushort_t tS[128 * 72];   // q/k transpose buffer
  const int tid = threadIdx.x;
  const int lane = tid & 63, wave = tid >> 6;
  const int quad = lane >> 4, l16 = lane & 15;
  const int wm = wave & 1, wn = wave >> 1;
  const int bm = blockIdx.x;

  if constexpr (MODE == 0) {
    // ---- fused LayerNorm staging: 128 rows of x[.][180] f32 -> bf16 aS ----
    const float* xb = x + (size_t)bm * 128 * CDIM;
    const int grp = tid >> 4, gl = tid & 15;
    float wv[12], bvv[12];
    if (gl < 15) {
      #pragma unroll
      for (int e = 0; e < 3; ++e) {
        float4 w4 = *reinterpret_cast<const float4*>(nw + gl * 12 + e * 4);
        float4 b4 = *reinterpret_cast<const float4*>(nb + gl * 12 + e * 4);
        wv[e*4+0] = w4.x; wv[e*4+1] = w4.y; wv[e*4+2] = w4.z; wv[e*4+3] = w4.w;
        bvv[e*4+0] = b4.x; bvv[e*4+1] = b4.y; bvv[e*4+2] = b4.z; bvv[e*4+3] = b4.w;
      }
    } else {
      #pragma unroll
      for (int k = 0; k < 12; ++k) { wv[k] = 0.f; bvv[k] = 0.f; }
    }
    #pragma unroll 2
    for (int i = 0; i < 8; ++i) {
      const int row = i * 16 + grp;
      const float* xr = xb + (size_t)row * CDIM;
      float v[12];
      float sum = 0.f, sq = 0.f;
      if (gl < 15) {
        #pragma unroll
        for (int e = 0; e < 3; ++e) {
          float4 x4 = *reinterpret_cast<const float4*>(xr + gl * 12 + e * 4);
          v[e*4+0] = x4.x; v[e*4+1] = x4.y; v[e*4+2] = x4.z; v[e*4+3] = x4.w;
        }
        #pragma unroll
        for (int k = 0; k < 12; ++k) { sum += v[k]; sq += v[k] * v[k]; }
      } else {
        #pragma unroll
        for (int k = 0; k < 12; ++k) v[k] = 0.f;
      }
      #pragma unroll
      for (int off = 1; off < 16; off <<= 1) {
        sum += __shfl_xor(sum, off, 64);
        sq  += __shfl_xor(sq, off, 64);
      }
      const float inv_n = 1.0f / 180.0f;
      float mean = sum * inv_n;
      float var = sq * inv_n - mean * mean;
      float rs = rsqrtf(var + 1e-5f);
      unsigned u[6];
      #pragma unroll
      for (int p = 0; p < 6; ++p) {
        float a = (v[2*p]   - mean) * rs * wv[2*p]   + bvv[2*p];
        float b = (v[2*p+1] - mean) * rs * wv[2*p+1] + bvv[2*p+1];
        u[p] = (unsigned)f2bf(a) | ((unsigned)f2bf(b) << 16);
      }
      ushort_t* dst = &aS[row * 200 + gl * 12];
      uint2 w01; w01.x = u[0]; w01.y = u[1];
      uint2 w23; w23.x = u[2]; w23.y = u[3];
      uint2 w45; w45.x = u[4]; w45.y = u[5];
      *reinterpret_cast<uint2*>(dst)     = w01;
      *reinterpret_cast<uint2*>(dst + 4) = w23;
      *reinterpret_cast<uint2*>(dst + 8) = w45;
    }
  } else {
    // stage full A tile: 128 rows x 192 cols (bf16 input)
    const ushort_t* Ab = A + (size_t)bm * 128 * 192;
    #pragma unroll
    for (int it = 0; it < 12; ++it) {
      int f = it * 256 + tid;
      int row = f / 24, kq = f % 24;
      uint4 v = *reinterpret_cast<const uint4*>(Ab + row * 192 + kq * 8);
      *reinterpret_cast<uint4*>(&aS[row * 200 + kq * 8]) = v;
    }
  }
  __syncthreads();

  // W2 B-load: chunk (((tile*2+wn)*2+nt)*6+ks)*512 + lane*8; nt stride 3072
  auto ldB = [&](int tile, int ks, bf16x8* dst) {
    const ushort_t* p = Wt + (size_t)((tile * 2 + wn) * 12 + ks) * 512 + lane * 8;
    dst[0] = *reinterpret_cast<const bf16x8*>(p);
    dst[1] = *reinterpret_cast<const bf16x8*>(p + 3072);
  };

  bf16x8 bB0[2], bB1[2], bB2[2];
  ldB(0, 0, bB0);
  ldB(0, 1, bB1);

  for (int nt0 = 0; nt0 < NT; ++nt0) {
    const int ntn = (nt0 + 1 < NT) ? nt0 + 1 : 0;   // wrap: harmless redundant loads
    f32x4 acc[4][2] = {};

    // step KS: prefetch (PT,PKS) into PRE, compute with CUR
    #define GSTEP(KS, CUR, PRE, PT, PKS) do { \
      ldB(PT, PKS, PRE); \
      bf16x8 af[4]; \
      _Pragma("unroll") \
      for (int mt = 0; mt < 4; ++mt) \
        af[mt] = *reinterpret_cast<const bf16x8*>(&aS[(wm * 64 + mt * 16 + l16) * 200 + KS * 32 + quad * 8]); \
      _Pragma("unroll") \
      for (int mt = 0; mt < 4; ++mt) { \
        acc[mt][0] = __builtin_amdgcn_mfma_f32_16x16x32_bf16(af[mt], CUR[0], acc[mt][0], 0, 0, 0); \
        acc[mt][1] = __builtin_amdgcn_mfma_f32_16x16x32_bf16(af[mt], CUR[1], acc[mt][1], 0, 0, 0); \
      } \
    } while (0)

    GSTEP(0, bB0, bB2, nt0, 2);
    GSTEP(1, bB1, bB0, nt0, 3);
    GSTEP(2, bB2, bB1, nt0, 4);
    GSTEP(3, bB0, bB2, nt0, 5);
    GSTEP(4, bB1, bB0, ntn, 0);
    GSTEP(5, bB2, bB1, ntn, 1);
    #undef GSTEP

    if (MODE == 0 && nt0 < 6) {
      // ---- q/k epilogue via LDS transpose: coalesced 16B/lane stores ----
      #pragma unroll
      for (int mt = 0; mt < 4; ++mt) {
        int rloc = wm * 64 + mt * 16 + quad * 4;
        #pragma unroll
        for (int nt = 0; nt < 2; ++nt) {
          int cloc = wn * 32 + nt * 16 + l16;
          float bv = bias[nt0 * 64 + cloc];
          #pragma unroll
          for (int r = 0; r < 4; ++r)
            tS[(rloc + r) * 72 + cloc] = f2bf(acc[mt][nt][r] + bv);
        }
      }
      __syncthreads();
      ushort_t* dst = (nt0 < 3) ? (q_out + nt0 * 64) : (k_out + (nt0 - 3) * 64);
      #pragma unroll
      for (int i = 0; i < 4; ++i) {
        int rrow = wave * 32 + i * 8 + (lane >> 3);
        int ccol = (lane & 7) * 8;
        bf16x8 vv = *reinterpret_cast<const bf16x8*>(&tS[rrow * 72 + ccol]);
        *reinterpret_cast<bf16x8*>(dst + (size_t)(bm * 128 + rrow) * CPAD + ccol) = vv;
      }
      __syncthreads();
    } else {
      // V path (MODE 0, nt0>=6) and MODE 1: direct stores
      #pragma unroll
      for (int mt = 0; mt < 4; ++mt) {
        int row = bm * 128 + wm * 64 + mt * 16 + quad * 4;
        #pragma unroll
        for (int nt = 0; nt < 2; ++nt) {
          int ncol = nt0 * 64 + wn * 32 + nt * 16 + l16;
          float bv = bias[ncol];
          if (MODE == 0) {
            // V part: 4 consecutive tokens (row..row+3, row%4==0) for dim d
            int d = ncol - 384;
            unsigned p0 = pk_bf(acc[mt][nt][0] + bv, acc[mt][nt][1] + bv);
            unsigned p1 = pk_bf(acc[mt][nt][2] + bv, acc[mt][nt][3] + bv);
            uint2 val; val.x = p0; val.y = p1;
            // vt4 index = tok*192 rearranged: (tok>>2)*768 + d*4 + (tok&3)
            *reinterpret_cast<uint2*>(vt_out + (size_t)row * 192 + d * 4) = val;
          } else {
            #pragma unroll
            for (int r = 0; r < 4; ++r) {
              int rr = row + r;
              float v = acc[mt][nt][r] + bv;
              if (ncol < CDIM) outf[(size_t)rr * CDIM + ncol] = v + resid[(size_t)rr * CDIM + ncol];
            }
          }
        }
      }
    }
  }
}

// ---------------- attention: per (window, head) — round-10 config (proven) -
// 4-wave blocks: the 4 waves of a (w,h) block read byte-identical K/V lines;
// co-locating them preserves L1 sharing (r12: 1-wave blocks tripled FETCH).
// S^T = K·Q^T; C-layout of S^T == A-layout of PV MFMA under key permutation
// key(kt,m) = 8*(m>>2) + 4*kt + (m&3). V in group-of-4 layout vt4; OOB ->
// bias group/row at tok NTOK. Fixed-max softmax (Q pre-scaled); l via V
// ones-column (d30). Interior: clamp-free offsets, depth-2 pipeline.
// Border: clamped depth-1 ping-pong.
__global__ __launch_bounds__(256, 4) void attn_k(const ushort_t* __restrict__ q_tok,
    const ushort_t* __restrict__ k_tok, const ushort_t* __restrict__ vt4,
    ushort_t* __restrict__ ao)
{
  const int w = blockIdx.x, h = blockIdx.y;
  const int tid = threadIdx.x;
  const int lane = tid & 63, wave = tid >> 6;
  const int quad = lane >> 4, l16 = lane & 15;
  const int wy = w >> 4, wx = w & 15;
  const int tok0 = wy * 16 * 256 + wx * 16;
  const int hc = h * 32;
  const int ybase = wy * 16 - 4, xbase = wx * 16 - 4;

  // Q fragments (B-operand layout), 4 q-tiles of 16
  bf16x8 qf[4];
  #pragma unroll
  for (int qt = 0; qt < 4; ++qt) {
    int qi = wave * 64 + qt * 16 + l16;
    int token = tok0 + (qi >> 4) * 256 + (qi & 15);
    qf[qt] = *reinterpret_cast<const bf16x8*>(q_tok + (size_t)token * CPAD + hc + quad * 8);
  }

  // permuted key id for the K A-frag gather
  const int key0 = ((l16 >> 2) << 3) + (l16 & 3);

  f32x4 o[4][2] = {};
  f32x4 zero = {0.f, 0.f, 0.f, 0.f};

  // shared compute step: S^T = K Q^T (pre-scaled), raw v_exp, pack P, PV
  auto compute = [&](const bf16x8* kf, const uint2* va, const uint2* vb) {
    bf16x8 vf0, vf1;
    {
      union { unsigned u[4]; bf16x8 v; } a_;
      a_.u[0] = va[0].x; a_.u[1] = va[0].y; a_.u[2] = va[1].x; a_.u[3] = va[1].y;
      vf0 = a_.v;
      a_.u[0] = vb[0].x; a_.u[1] = vb[0].y; a_.u[2] = vb[1].x; a_.u[3] = vb[1].y;
      vf1 = a_.v;
    }
    __builtin_amdgcn_s_setprio(1);
    #pragma unroll
    for (int qt = 0; qt < 4; ++qt) {
      f32x4 s0 = __builtin_amdgcn_mfma_f32_16x16x32_bf16(kf[0], qf[qt], zero, 0, 0, 0);
      f32x4 s1 = __builtin_amdgcn_mfma_f32_16x16x32_bf16(kf[1], qf[qt], zero, 0, 0, 0);
      union { unsigned u[4]; bf16x8 v; } pk;
      pk.u[0] = pk_bf(__builtin_amdgcn_exp2f(s0[0]), __builtin_amdgcn_exp2f(s0[1]));
      pk.u[1] = pk_bf(__builtin_amdgcn_exp2f(s0[2]), __builtin_amdgcn_exp2f(s0[3]));
      pk.u[2] = pk_bf(__builtin_amdgcn_exp2f(s1[0]), __builtin_amdgcn_exp2f(s1[1]));
      pk.u[3] = pk_bf(__builtin_amdgcn_exp2f(s1[2]), __builtin_amdgcn_exp2f(s1[3]));
      o[qt][0] = __builtin_amdgcn_mfma_f32_16x16x32_bf16(pk.v, vf0, o[qt][0], 0, 0, 0);
      o[qt][1] = __builtin_amdgcn_mfma_f32_16x16x32_bf16(pk.v, vf1, o[qt][1], 0, 0, 0);
    }
    __builtin_amdgcn_s_setprio(0);
  };

  const bool interior = ((unsigned)(wy - 1) < 14u) && ((unsigned)(wx - 1) < 14u);

  if (interior) {
    // ---- interior: clamp-free byte-offset addressing, depth-2 pipeline ----
    unsigned koff[3][2], voff[3][2];
    #pragma unroll
    for (int cm = 0; cm < 3; ++cm) {
      #pragma unroll
      for (int j = 0; j < 2; ++j) {
        int pk = 32 * cm + key0 + 4 * j;
        int py = pk / 24, px = pk - py * 24;
        koff[cm][j] = (unsigned)((((ybase + py) * 256 + xbase + px) * 384) + (hc + quad * 8) * 2);
        int pv = 32 * cm + quad * 8 + 4 * j;
        int pyv = pv / 24, pxv = pv - pyv * 24;
        voff[cm][j] = (unsigned)((((ybase + pyv) * 256 + xbase + pxv) * 384) + (hc + l16) * 8);
      }
    }
    const char* kp = (const char*)k_tok;
    const char* vp = (const char*)vt4;
    auto lK = [&](int c, bf16x8* kf) {
      const int cm = c % 3; const unsigned cb = (unsigned)(c / 3) * 393216u;
      #pragma unroll
      for (int kt = 0; kt < 2; ++kt)
        kf[kt] = *reinterpret_cast<const bf16x8*>(kp + (size_t)(koff[cm][kt] + cb));
    };
    auto lV = [&](int c, uint2* va, uint2* vb) {
      const int cm = c % 3; const unsigned cb = (unsigned)(c / 3) * 393216u;
      #pragma unroll
      for (int h2 = 0; h2 < 2; ++h2) {
        const char* g = vp + (size_t)(voff[cm][h2] + cb);
        va[h2] = *reinterpret_cast<const uint2*>(g);        // dims l16
        vb[h2] = *reinterpret_cast<const uint2*>(g + 128);  // dims 16+l16
      }
    };
    bf16x8 kbuf[3][2]; uint2 vabuf[3][2], vbbuf[3][2];
    lK(0, kbuf[0]); lV(0, vabuf[0], vbbuf[0]);
    lK(1, kbuf[1]); lV(1, vabuf[1], vbbuf[1]);
    #pragma unroll
    for (int c = 0; c < 18; ++c) {
      const int cur = c % 3, nxt = (c + 2) % 3;   // literals after unroll
      if (c < 16) { lK(c + 2, kbuf[nxt]); lV(c + 2, vabuf[nxt], vbbuf[nxt]); }
      compute(kbuf[cur], vabuf[cur], vbbuf[cur]);
    }
  } else {
    // ---- border: clamped path, depth-1 ping-pong ----
    int kpy[3][2], ktx[3][2]; bool kxin[3][2];
    int vpy[3][2], vtx[3][2]; bool vxin[3][2];
    #pragma unroll
    for (int cm = 0; cm < 3; ++cm) {
      #pragma unroll
      for (int j = 0; j < 2; ++j) {
        int pk = 32 * cm + key0 + 4 * j;
        int py = pk / 24, px = pk - py * 24;
        kpy[cm][j] = py; ktx[cm][j] = xbase + px;
        kxin[cm][j] = (unsigned)(xbase + px) < 256u;
        int pv = 32 * cm + quad * 8 + 4 * j;
        int pyv = pv / 24, pxv = pv - pyv * 24;
        vpy[cm][j] = pyv; vtx[cm][j] = xbase + pxv;
        vxin[cm][j] = (unsigned)(xbase + pxv) < 256u;
      }
    }
    const int dOff0 = (hc + l16) * 4, dOff1 = (hc + 16 + l16) * 4;
    auto loadK = [&](int c, bf16x8* kf) {
      const int cm = c % 3, c3 = c / 3;
      const int yrow = ybase + 4 * c3;
      #pragma unroll
      for (int kt = 0; kt < 2; ++kt) {
        int y = yrow + kpy[cm][kt];
        bool inb = kxin[cm][kt] && ((unsigned)y < 256u);
        int t = inb ? (y * 256 + ktx[cm][kt]) : NTOK;
        kf[kt] = *reinterpret_cast<const bf16x8*>(k_tok + (size_t)t * CPAD + hc + quad * 8);
      }
    };
    auto loadV = [&](int c, uint2* va, uint2* vb) {
      const int cm = c % 3, c3 = c / 3;
      const int yrow = ybase + 4 * c3;
      #pragma unroll
      for (int h2 = 0; h2 < 2; ++h2) {
        int y = yrow + vpy[cm][h2];
        bool inb = vxin[cm][h2] && ((unsigned)y < 256u);
        int t = inb ? (y * 256 + vtx[cm][h2]) : NTOK;
        const ushort_t* gp = vt4 + (size_t)t * 192;
        va[h2] = *reinterpret_cast<const uint2*>(gp + dOff0);
        vb[h2] = *reinterpret_cast<const uint2*>(gp + dOff1);
      }
    };
    bf16x8 kbuf[2][2]; uint2 vabuf[2][2], vbbuf[2][2];
    loadK(0, kbuf[0]); loadV(0, vabuf[0], vbbuf[0]);
    #pragma unroll
    for (int c = 0; c < 18; ++c) {
      const int cur = c & 1, nxt = cur ^ 1;
      if (c < 17) { loadK(c + 1, kbuf[nxt]); loadV(c + 1, vabuf[nxt], vbbuf[nxt]); }
      compute(kbuf[cur], vabuf[cur], vbbuf[cur]);
    }
  }

  // ---- epilogue: l = O[:,30] (ones-column), O /= l, scatter
  #pragma unroll
  for (int qt = 0; qt < 4; ++qt) {
    #pragma unroll
    for (int r = 0; r < 4; ++r) {
      float l = __shfl(o[qt][1][r], (lane & 48) + 14, 64);
      float inv = 1.0f / l;
      int qi = wave * 64 + qt * 16 + quad * 4 + r;
      int token = tok0 + (qi >> 4) * 256 + (qi & 15);
      ao[(size_t)token * CPAD + hc + l16]      = f2bf(o[qt][0][r] * inv);
      ao[(size_t)token * CPAD + hc + 16 + l16] = f2bf(o[qt][1][r] * inv);
    }
  }
}

// ---------------- launch ----------------
extern "C" void kernel_launch(void* const* d_in, const int* in_sizes, int n_in,
                              void* d_out, int out_size, void* d_ws, size_t ws_size,
                              hipStream_t stream) {
  const float* x      = (const float*)d_in[0];
  const float* norm_w = (const float*)d_in[1];
  const float* norm_b = (const float*)d_in[2];
  const float* q_w    = (const float*)d_in[3];
  const float* q_b    = (const float*)d_in[4];
  const float* kv_w   = (const float*)d_in[5];
  const float* kv_b   = (const float*)d_in[6];
  const float* p_w    = (const float*)d_in[7];
  const float* p_b    = (const float*)d_in[8];

  char* base = (char*)d_ws;
  size_t off = 0;
  auto alloc = [&](size_t bytes) { char* p = base + off; off = (off + bytes + 255) & ~(size_t)255; return p; };
  ushort_t* ao    = (ushort_t*)alloc((size_t)NTOK * CPAD * 2);
  ushort_t* q_tok = (ushort_t*)alloc((size_t)NTOK * CPAD * 2);
  ushort_t* k_tok = (ushort_t*)alloc((size_t)(NTOK + 1) * CPAD * 2);  // +1 bias row
  ushort_t* vt4   = (ushort_t*)alloc((size_t)(NTOK + 4) * 192 * 2);   // +1 bias group
  ushort_t* wqkvt = (ushort_t*)alloc(576 * 192 * 2);
  ushort_t* pwt   = (ushort_t*)alloc(192 * 192 * 2);
  float* qkvb = (float*)alloc(576 * 4);
  float* pbp  = (float*)alloc(192 * 4);

  prep_k<<<583, 256, 0, stream>>>(q_w, q_b, kv_w, kv_b, p_w, p_b,
                                  wqkvt, pwt, qkvb, pbp,
                                  k_tok + (size_t)NTOK * CPAD,
                                  vt4 + (size_t)NTOK * 192);
  // LN fused into gemm_k<0> staging; BM=128, grid 512; W2 B-layout
  gemm_k<0><<<NTOK / 128, 256, 0, stream>>>(nullptr, x, norm_w, norm_b,
                                            wqkvt, qkvb, q_tok, k_tok, vt4, nullptr, nullptr);
  // attn: round-10 4-wave blocks (proven 52.7us)
  attn_k<<<dim3(256, 6), 256, 0, stream>>>(q_tok, k_tok, vt4, ao);
  gemm_k<1><<<NTOK / 128, 256, 0, stream>>>(ao, nullptr, nullptr, nullptr,
                                            pwt, pbp, nullptr, nullptr, nullptr, (float*)d_out, x);
}